// Round 1
// baseline (3171.005 us; speedup 1.0000x reference)
//
#include <hip/hip_runtime.h>

#define N_NODES   100000
#define E_EDGES   1600000
#define IN_FEATS  128
#define OUT_FEATS 64
#define NH        8
#define DK        8

// ---------------------------------------------------------------------------
// QKV projection: per block, 64 rows x 64 outs for each of Wq/Wk/Wv.
// x tile in LDS (pad 132 -> conflict-free scalar row reads, float4-aligned
// stores); W staged transposed wt[i][o] (pad 72 -> float4-aligned compute
// reads, 2-way-max bank aliasing which is free on gfx950).
// ---------------------------------------------------------------------------
__global__ __launch_bounds__(256) void qkv_kernel(
    const float* __restrict__ x,
    const float* __restrict__ Wq, const float* __restrict__ bq,
    const float* __restrict__ Wk, const float* __restrict__ bk,
    const float* __restrict__ Wv, const float* __restrict__ bv,
    float* __restrict__ qo, float* __restrict__ ko, float* __restrict__ vo)
{
    __shared__ float xs[64][132];
    __shared__ float wt[128][72];

    const int t    = threadIdx.x;
    const int row0 = blockIdx.x * 64;

    // Stage x tile: coalesced global float4 reads, float4 LDS writes.
    for (int idx = t; idx < 64 * 32; idx += 256) {
        const int r   = idx >> 5;
        const int c4  = idx & 31;
        const int row = row0 + r;
        float4 val = make_float4(0.f, 0.f, 0.f, 0.f);
        if (row < N_NODES)
            val = ((const float4*)(x + (size_t)row * IN_FEATS))[c4];
        *(float4*)&xs[r][c4 * 4] = val;
    }

    const int ot = t & 15;   // output cols 4*ot .. 4*ot+3
    const int rt = t >> 4;   // rows        4*rt .. 4*rt+3

    const float* Wm[3] = {Wq, Wk, Wv};
    const float* bm[3] = {bq, bk, bv};
    float*       om[3] = {qo, ko, vo};

    for (int m = 0; m < 3; ++m) {
        __syncthreads();   // protect wt from previous iteration's readers
        const float* W = Wm[m];
        // Stage W transposed: wt[i][o] = W[o][i].
        // Lanes walk o (uncoalesced global reads, but W is 32 KB and L2-hot
        // across all 1563 blocks); LDS writes are consecutive -> conflict-free.
        for (int idx = t; idx < 64 * 32; idx += 256) {
            const int o  = idx & 63;
            const int i4 = idx >> 6;
            const float4 val = ((const float4*)(W + o * IN_FEATS))[i4];
            wt[i4 * 4 + 0][o] = val.x;
            wt[i4 * 4 + 1][o] = val.y;
            wt[i4 * 4 + 2][o] = val.z;
            wt[i4 * 4 + 3][o] = val.w;
        }
        __syncthreads();

        const float* b = bm[m];
        float acc[4][4];
        #pragma unroll
        for (int jo = 0; jo < 4; ++jo) {
            const float bb = b[4 * ot + jo];
            #pragma unroll
            for (int jr = 0; jr < 4; ++jr) acc[jr][jo] = bb;
        }

        #pragma unroll 4
        for (int i = 0; i < IN_FEATS; ++i) {
            const float4 w4 = *(const float4*)&wt[i][4 * ot];
            #pragma unroll
            for (int jr = 0; jr < 4; ++jr) {
                const float xv = xs[4 * rt + jr][i];
                acc[jr][0] += xv * w4.x;
                acc[jr][1] += xv * w4.y;
                acc[jr][2] += xv * w4.z;
                acc[jr][3] += xv * w4.w;
            }
        }

        float* dsto = om[m];
        #pragma unroll
        for (int jr = 0; jr < 4; ++jr) {
            const int row = row0 + 4 * rt + jr;
            if (row < N_NODES)
                ((float4*)(dsto + (size_t)row * OUT_FEATS))[ot] =
                    make_float4(acc[jr][0], acc[jr][1], acc[jr][2], acc[jr][3]);
        }
    }
}

// ---------------------------------------------------------------------------
// Pass B: one thread per (edge, head). Scores are tiny (|s| << 1) so we skip
// the segment-max shift (identical up to the 1e-16 epsilon term).
// ---------------------------------------------------------------------------
__global__ __launch_bounds__(256) void score_kernel(
    const float* __restrict__ q, const float* __restrict__ k,
    const int* __restrict__ src, const int* __restrict__ dst,
    float* __restrict__ exb, float* __restrict__ denom)
{
    const int tid = blockIdx.x * 256 + threadIdx.x;
    if (tid >= E_EDGES * NH) return;
    const int e = tid >> 3;
    const int h = tid & 7;
    const int s = src[e];
    const int d = dst[e];
    const float4* qp = (const float4*)(q + (size_t)s * OUT_FEATS + h * DK);
    const float4* kp = (const float4*)(k + (size_t)d * OUT_FEATS + h * DK);
    const float4 q0 = qp[0], q1 = qp[1];
    const float4 k0 = kp[0], k1 = kp[1];
    const float dot = q0.x * k0.x + q0.y * k0.y + q0.z * k0.z + q0.w * k0.w +
                      q1.x * k1.x + q1.y * k1.y + q1.z * k1.z + q1.w * k1.w;
    const float ex = __expf(dot * 0.3535533905932738f);   // 1/sqrt(8)
    exb[tid] = ex;
    unsafeAtomicAdd(&denom[s * NH + h], ex);
}

// ---------------------------------------------------------------------------
// Pass C: normalize and scatter attn * v[dst] into out[src].
// ---------------------------------------------------------------------------
__global__ __launch_bounds__(256) void scatter_kernel(
    const float* __restrict__ v,
    const int* __restrict__ src, const int* __restrict__ dst,
    const float* __restrict__ exb, const float* __restrict__ denom,
    float* __restrict__ out)
{
    const int tid = blockIdx.x * 256 + threadIdx.x;
    if (tid >= E_EDGES * NH) return;
    const int e = tid >> 3;
    const int h = tid & 7;
    const int s = src[e];
    const int d = dst[e];
    const float a = exb[tid] / (denom[s * NH + h] + 1e-16f);
    const float4* vp = (const float4*)(v + (size_t)d * OUT_FEATS + h * DK);
    const float4 v0 = vp[0], v1 = vp[1];
    float* op = out + (size_t)s * OUT_FEATS + h * DK;
    unsafeAtomicAdd(op + 0, a * v0.x);
    unsafeAtomicAdd(op + 1, a * v0.y);
    unsafeAtomicAdd(op + 2, a * v0.z);
    unsafeAtomicAdd(op + 3, a * v0.w);
    unsafeAtomicAdd(op + 4, a * v1.x);
    unsafeAtomicAdd(op + 5, a * v1.y);
    unsafeAtomicAdd(op + 6, a * v1.z);
    unsafeAtomicAdd(op + 7, a * v1.w);
}

extern "C" void kernel_launch(void* const* d_in, const int* in_sizes, int n_in,
                              void* d_out, int out_size, void* d_ws, size_t ws_size,
                              hipStream_t stream)
{
    const float* x  = (const float*)d_in[0];
    const int*  edge = (const int*)d_in[1];
    const float* Wq = (const float*)d_in[2];
    const float* bq = (const float*)d_in[3];
    const float* Wk = (const float*)d_in[4];
    const float* bk = (const float*)d_in[5];
    const float* Wv = (const float*)d_in[6];
    const float* bv = (const float*)d_in[7];
    float* out = (float*)d_out;

    // Workspace layout (fp32): q | k | v | ex[E*8] | denom[N*8]  (~131 MB)
    float* q     = (float*)d_ws;
    float* k     = q + (size_t)N_NODES * OUT_FEATS;
    float* v     = k + (size_t)N_NODES * OUT_FEATS;
    float* exb   = v + (size_t)N_NODES * OUT_FEATS;
    float* denom = exb + (size_t)E_EDGES * NH;

    const int* src = edge;            // edge[0] = source (softmax group / out row)
    const int* dst = edge + E_EDGES;  // edge[1] = destination (k/v gather)

    hipMemsetAsync(out,   0, (size_t)N_NODES * OUT_FEATS * sizeof(float), stream);
    hipMemsetAsync(denom, 0, (size_t)N_NODES * NH * sizeof(float), stream);

    qkv_kernel<<<(N_NODES + 63) / 64, 256, 0, stream>>>(
        x, Wq, bq, Wk, bk, Wv, bv, q, k, v);

    const int nt = E_EDGES * NH;
    score_kernel<<<(nt + 255) / 256, 256, 0, stream>>>(q, k, src, dst, exb, denom);
    scatter_kernel<<<(nt + 255) / 256, 256, 0, stream>>>(v, src, dst, exb, denom, out);
}

// Round 2
// 538.255 us; speedup vs baseline: 5.8913x; 5.8913x over previous
//
#include <hip/hip_runtime.h>

#define N_NODES   100000
#define E_EDGES   1600000
#define IN_FEATS  128
#define OUT_FEATS 64
#define NH        8
#define DK        8

#define SCAN_BLOCKS ((N_NODES + 255) / 256)   // 391

// ---------------------------------------------------------------------------
// QKV projection: per block, 64 rows x 64 outs for each of Wq/Wk/Wv.
// ---------------------------------------------------------------------------
__global__ __launch_bounds__(256) void qkv_kernel(
    const float* __restrict__ x,
    const float* __restrict__ Wq, const float* __restrict__ bq,
    const float* __restrict__ Wk, const float* __restrict__ bk,
    const float* __restrict__ Wv, const float* __restrict__ bv,
    float* __restrict__ qo, float* __restrict__ ko, float* __restrict__ vo)
{
    __shared__ float xs[64][132];
    __shared__ float wt[128][72];

    const int t    = threadIdx.x;
    const int row0 = blockIdx.x * 64;

    for (int idx = t; idx < 64 * 32; idx += 256) {
        const int r   = idx >> 5;
        const int c4  = idx & 31;
        const int row = row0 + r;
        float4 val = make_float4(0.f, 0.f, 0.f, 0.f);
        if (row < N_NODES)
            val = ((const float4*)(x + (size_t)row * IN_FEATS))[c4];
        *(float4*)&xs[r][c4 * 4] = val;
    }

    const int ot = t & 15;
    const int rt = t >> 4;

    const float* Wm[3] = {Wq, Wk, Wv};
    const float* bm[3] = {bq, bk, bv};
    float*       om[3] = {qo, ko, vo};

    for (int m = 0; m < 3; ++m) {
        __syncthreads();
        const float* W = Wm[m];
        for (int idx = t; idx < 64 * 32; idx += 256) {
            const int o  = idx & 63;
            const int i4 = idx >> 6;
            const float4 val = ((const float4*)(W + o * IN_FEATS))[i4];
            wt[i4 * 4 + 0][o] = val.x;
            wt[i4 * 4 + 1][o] = val.y;
            wt[i4 * 4 + 2][o] = val.z;
            wt[i4 * 4 + 3][o] = val.w;
        }
        __syncthreads();

        const float* b = bm[m];
        float acc[4][4];
        #pragma unroll
        for (int jo = 0; jo < 4; ++jo) {
            const float bb = b[4 * ot + jo];
            #pragma unroll
            for (int jr = 0; jr < 4; ++jr) acc[jr][jo] = bb;
        }

        #pragma unroll 4
        for (int i = 0; i < IN_FEATS; ++i) {
            const float4 w4 = *(const float4*)&wt[i][4 * ot];
            #pragma unroll
            for (int jr = 0; jr < 4; ++jr) {
                const float xv = xs[4 * rt + jr][i];
                acc[jr][0] += xv * w4.x;
                acc[jr][1] += xv * w4.y;
                acc[jr][2] += xv * w4.z;
                acc[jr][3] += xv * w4.w;
            }
        }

        float* dsto = om[m];
        #pragma unroll
        for (int jr = 0; jr < 4; ++jr) {
            const int row = row0 + 4 * rt + jr;
            if (row < N_NODES)
                ((float4*)(dsto + (size_t)row * OUT_FEATS))[ot] =
                    make_float4(acc[jr][0], acc[jr][1], acc[jr][2], acc[jr][3]);
        }
    }
}

// ---------------------------------------------------------------------------
// CSR build: degree histogram -> exclusive scan -> cursor scatter of dst.
// ---------------------------------------------------------------------------
__global__ __launch_bounds__(256) void hist_kernel(
    const int* __restrict__ src, int* __restrict__ cnt)
{
    const int e = blockIdx.x * 256 + threadIdx.x;
    if (e < E_EDGES) atomicAdd(&cnt[src[e]], 1);
}

__global__ __launch_bounds__(256) void scan1_kernel(
    const int* __restrict__ cnt, int* __restrict__ row_start,
    int* __restrict__ bsum)
{
    __shared__ int s[256];
    const int tid = threadIdx.x;
    const int i   = blockIdx.x * 256 + tid;
    const int v   = (i < N_NODES) ? cnt[i] : 0;
    int x = v;
    s[tid] = x;
    __syncthreads();
    for (int off = 1; off < 256; off <<= 1) {
        const int t = (tid >= off) ? s[tid - off] : 0;
        __syncthreads();
        x += t;
        s[tid] = x;
        __syncthreads();
    }
    if (i < N_NODES) row_start[i] = x - v;      // exclusive
    if (tid == 255)  bsum[blockIdx.x] = x;      // block total
}

__global__ __launch_bounds__(512) void scan2_kernel(int* __restrict__ bsum)
{
    __shared__ int s[512];
    const int tid = threadIdx.x;
    const int v   = (tid < SCAN_BLOCKS) ? bsum[tid] : 0;
    int x = v;
    s[tid] = x;
    __syncthreads();
    for (int off = 1; off < 512; off <<= 1) {
        const int t = (tid >= off) ? s[tid - off] : 0;
        __syncthreads();
        x += t;
        s[tid] = x;
        __syncthreads();
    }
    if (tid < SCAN_BLOCKS) bsum[tid] = x - v;   // exclusive
}

__global__ __launch_bounds__(256) void scan3_kernel(
    int* __restrict__ row_start, const int* __restrict__ bsum)
{
    const int i = blockIdx.x * 256 + threadIdx.x;
    if (i < N_NODES) row_start[i] += bsum[blockIdx.x];
}

__global__ __launch_bounds__(256) void csr_scatter_kernel(
    const int* __restrict__ src, const int* __restrict__ dst,
    const int* __restrict__ row_start, int* __restrict__ cursor,
    int* __restrict__ csr_dst)
{
    const int e = blockIdx.x * 256 + threadIdx.x;
    if (e >= E_EDGES) return;
    const int s   = src[e];
    const int pos = atomicAdd(&cursor[s], 1);
    csr_dst[row_start[s] + pos] = dst[e];
}

// ---------------------------------------------------------------------------
// Fused attention: one wave per node. lane = h*8 + d holds out column `lane`.
// Single softmax pass (no max shift needed: |scores| << 1):
//   out = sum_e ex_e * v[dst_e] / (sum_e ex_e + 1e-16)
// ---------------------------------------------------------------------------
__global__ __launch_bounds__(256) void attn_kernel(
    const float* __restrict__ q, const float* __restrict__ k,
    const float* __restrict__ v,
    const int* __restrict__ row_start, const int* __restrict__ cnt,
    const int* __restrict__ csr_dst, float* __restrict__ out)
{
    const int lane = threadIdx.x & 63;
    const int wv   = threadIdx.x >> 6;
    const int node = blockIdx.x * 4 + wv;     // grid sized so node < N_NODES

    const float qv    = q[(size_t)node * OUT_FEATS + lane];
    const int   start = row_start[node];
    const int   deg   = cnt[node];

    float den = 0.f, acc = 0.f;
    for (int j = 0; j < deg; ++j) {
        const int dn = csr_dst[start + j];
        const float kv = k[(size_t)dn * OUT_FEATS + lane];
        float p = qv * kv;
        p += __shfl_xor(p, 1);
        p += __shfl_xor(p, 2);
        p += __shfl_xor(p, 4);                // dot over d within each head
        const float ex = __expf(p * 0.3535533905932738f);
        const float vv = v[(size_t)dn * OUT_FEATS + lane];
        den += ex;
        acc += ex * vv;
    }
    out[(size_t)node * OUT_FEATS + lane] = acc / (den + 1e-16f);
}

extern "C" void kernel_launch(void* const* d_in, const int* in_sizes, int n_in,
                              void* d_out, int out_size, void* d_ws, size_t ws_size,
                              hipStream_t stream)
{
    const float* x  = (const float*)d_in[0];
    const int*  edge = (const int*)d_in[1];
    const float* Wq = (const float*)d_in[2];
    const float* bq = (const float*)d_in[3];
    const float* Wk = (const float*)d_in[4];
    const float* bk = (const float*)d_in[5];
    const float* Wv = (const float*)d_in[6];
    const float* bv = (const float*)d_in[7];
    float* out = (float*)d_out;

    // Workspace: q | k | v | cnt | row_start | cursor | bsum | csr_dst
    float* q  = (float*)d_ws;
    float* k  = q + (size_t)N_NODES * OUT_FEATS;
    float* v  = k + (size_t)N_NODES * OUT_FEATS;
    int* cnt       = (int*)(v + (size_t)N_NODES * OUT_FEATS);
    int* row_start = cnt + N_NODES;
    int* cursor    = row_start + N_NODES;
    int* bsum      = cursor + N_NODES;
    int* csr_dst   = bsum + ((SCAN_BLOCKS + 511) / 512) * 512;

    const int* src = edge;            // edge[0]
    const int* dst = edge + E_EDGES;  // edge[1]

    hipMemsetAsync(cnt,    0, N_NODES * sizeof(int), stream);
    hipMemsetAsync(cursor, 0, N_NODES * sizeof(int), stream);

    qkv_kernel<<<(N_NODES + 63) / 64, 256, 0, stream>>>(
        x, Wq, bq, Wk, bk, Wv, bv, q, k, v);

    const int eblocks = (E_EDGES + 255) / 256;
    hist_kernel<<<eblocks, 256, 0, stream>>>(src, cnt);
    scan1_kernel<<<SCAN_BLOCKS, 256, 0, stream>>>(cnt, row_start, bsum);
    scan2_kernel<<<1, 512, 0, stream>>>(bsum);
    scan3_kernel<<<SCAN_BLOCKS, 256, 0, stream>>>(row_start, bsum);
    csr_scatter_kernel<<<eblocks, 256, 0, stream>>>(src, dst, row_start, cursor, csr_dst);

    attn_kernel<<<N_NODES / 4, 256, 0, stream>>>(q, k, v, row_start, cnt, csr_dst, out);
}

// Round 3
// 421.332 us; speedup vs baseline: 7.5261x; 1.2775x over previous
//
#include <hip/hip_runtime.h>

#define N_NODES   100000
#define E_EDGES   1600000
#define IN_FEATS  128
#define OUT_FEATS 64
#define NH        8
#define DK        8

#define SCAN_BLOCKS ((N_NODES + 255) / 256)   // 391

// ---------------------------------------------------------------------------
// QKV projection: per block, 64 rows x 64 outs for each of Wq/Wk/Wv.
// ---------------------------------------------------------------------------
__global__ __launch_bounds__(256) void qkv_kernel(
    const float* __restrict__ x,
    const float* __restrict__ Wq, const float* __restrict__ bq,
    const float* __restrict__ Wk, const float* __restrict__ bk,
    const float* __restrict__ Wv, const float* __restrict__ bv,
    float* __restrict__ qo, float* __restrict__ ko, float* __restrict__ vo)
{
    __shared__ float xs[64][132];
    __shared__ float wt[128][72];

    const int t    = threadIdx.x;
    const int row0 = blockIdx.x * 64;

    for (int idx = t; idx < 64 * 32; idx += 256) {
        const int r   = idx >> 5;
        const int c4  = idx & 31;
        const int row = row0 + r;
        float4 val = make_float4(0.f, 0.f, 0.f, 0.f);
        if (row < N_NODES)
            val = ((const float4*)(x + (size_t)row * IN_FEATS))[c4];
        *(float4*)&xs[r][c4 * 4] = val;
    }

    const int ot = t & 15;
    const int rt = t >> 4;

    const float* Wm[3] = {Wq, Wk, Wv};
    const float* bm[3] = {bq, bk, bv};
    float*       om[3] = {qo, ko, vo};

    for (int m = 0; m < 3; ++m) {
        __syncthreads();
        const float* W = Wm[m];
        for (int idx = t; idx < 64 * 32; idx += 256) {
            const int o  = idx & 63;
            const int i4 = idx >> 6;
            const float4 val = ((const float4*)(W + o * IN_FEATS))[i4];
            wt[i4 * 4 + 0][o] = val.x;
            wt[i4 * 4 + 1][o] = val.y;
            wt[i4 * 4 + 2][o] = val.z;
            wt[i4 * 4 + 3][o] = val.w;
        }
        __syncthreads();

        const float* b = bm[m];
        float acc[4][4];
        #pragma unroll
        for (int jo = 0; jo < 4; ++jo) {
            const float bb = b[4 * ot + jo];
            #pragma unroll
            for (int jr = 0; jr < 4; ++jr) acc[jr][jo] = bb;
        }

        #pragma unroll 4
        for (int i = 0; i < IN_FEATS; ++i) {
            const float4 w4 = *(const float4*)&wt[i][4 * ot];
            #pragma unroll
            for (int jr = 0; jr < 4; ++jr) {
                const float xv = xs[4 * rt + jr][i];
                acc[jr][0] += xv * w4.x;
                acc[jr][1] += xv * w4.y;
                acc[jr][2] += xv * w4.z;
                acc[jr][3] += xv * w4.w;
            }
        }

        float* dsto = om[m];
        #pragma unroll
        for (int jr = 0; jr < 4; ++jr) {
            const int row = row0 + 4 * rt + jr;
            if (row < N_NODES)
                ((float4*)(dsto + (size_t)row * OUT_FEATS))[ot] =
                    make_float4(acc[jr][0], acc[jr][1], acc[jr][2], acc[jr][3]);
        }
    }
}

// ---------------------------------------------------------------------------
// CSR build: histogram captures per-edge position -> scan -> atomic-free
// scatter. Block-offset add (old scan3) is folded into the consumers.
// ---------------------------------------------------------------------------
__global__ __launch_bounds__(256) void hist_kernel(
    const int* __restrict__ src, int* __restrict__ cnt, int* __restrict__ pos_e)
{
    const int e = blockIdx.x * 256 + threadIdx.x;
    if (e < E_EDGES) pos_e[e] = atomicAdd(&cnt[src[e]], 1);
}

__global__ __launch_bounds__(256) void scan1_kernel(
    const int* __restrict__ cnt, int* __restrict__ row_start,
    int* __restrict__ bsum)
{
    __shared__ int s[256];
    const int tid = threadIdx.x;
    const int i   = blockIdx.x * 256 + tid;
    const int v   = (i < N_NODES) ? cnt[i] : 0;
    int x = v;
    s[tid] = x;
    __syncthreads();
    for (int off = 1; off < 256; off <<= 1) {
        const int t = (tid >= off) ? s[tid - off] : 0;
        __syncthreads();
        x += t;
        s[tid] = x;
        __syncthreads();
    }
    if (i < N_NODES) row_start[i] = x - v;      // exclusive within block
    if (tid == 255)  bsum[blockIdx.x] = x;      // block total
}

__global__ __launch_bounds__(512) void scan2_kernel(int* __restrict__ bsum)
{
    __shared__ int s[512];
    const int tid = threadIdx.x;
    const int v   = (tid < SCAN_BLOCKS) ? bsum[tid] : 0;
    int x = v;
    s[tid] = x;
    __syncthreads();
    for (int off = 1; off < 512; off <<= 1) {
        const int t = (tid >= off) ? s[tid - off] : 0;
        __syncthreads();
        x += t;
        s[tid] = x;
        __syncthreads();
    }
    if (tid < SCAN_BLOCKS) bsum[tid] = x - v;   // exclusive block offsets
}

__global__ __launch_bounds__(256) void csr_scatter_kernel(
    const int* __restrict__ src, const int* __restrict__ dst,
    const int* __restrict__ row_start, const int* __restrict__ bsum,
    const int* __restrict__ pos_e, int* __restrict__ csr_dst)
{
    const int e = blockIdx.x * 256 + threadIdx.x;
    if (e >= E_EDGES) return;
    const int s = src[e];
    csr_dst[row_start[s] + bsum[s >> 8] + pos_e[e]] = dst[e];
}

// ---------------------------------------------------------------------------
// Fused attention: one wave per node; lane = h*8+d owns out column `lane`.
// Edge indices prefetched 64-at-a-time (one coalesced load) and broadcast
// via shfl; edge loop unrolled x4 so 8 independent 256B row-gathers are in
// flight per group (MLP 2 -> 8).
// ---------------------------------------------------------------------------
__global__ __launch_bounds__(256) void attn_kernel(
    const float* __restrict__ q, const float* __restrict__ k,
    const float* __restrict__ v,
    const int* __restrict__ row_start, const int* __restrict__ bsum,
    const int* __restrict__ cnt,
    const int* __restrict__ csr_dst, float* __restrict__ out)
{
    const int lane = threadIdx.x & 63;
    const int wv   = threadIdx.x >> 6;
    const int node = blockIdx.x * 4 + wv;     // grid = N/4 exactly

    const float qv    = q[(size_t)node * OUT_FEATS + lane];
    const int   start = row_start[node] + bsum[node >> 8];
    const int   deg   = cnt[node];

    float den = 0.f, acc = 0.f;
    for (int base = 0; base < deg; base += 64) {
        const int rem = deg - base;
        const int nj  = rem < 64 ? rem : 64;
        int dn_lane = 0;
        if (lane < nj) dn_lane = csr_dst[start + base + lane];

        int j = 0;
        for (; j + 4 <= nj; j += 4) {
            const int dn0 = __shfl(dn_lane, j + 0);
            const int dn1 = __shfl(dn_lane, j + 1);
            const int dn2 = __shfl(dn_lane, j + 2);
            const int dn3 = __shfl(dn_lane, j + 3);
            const float kv0 = k[(size_t)dn0 * OUT_FEATS + lane];
            const float kv1 = k[(size_t)dn1 * OUT_FEATS + lane];
            const float kv2 = k[(size_t)dn2 * OUT_FEATS + lane];
            const float kv3 = k[(size_t)dn3 * OUT_FEATS + lane];
            const float vv0 = v[(size_t)dn0 * OUT_FEATS + lane];
            const float vv1 = v[(size_t)dn1 * OUT_FEATS + lane];
            const float vv2 = v[(size_t)dn2 * OUT_FEATS + lane];
            const float vv3 = v[(size_t)dn3 * OUT_FEATS + lane];

            float p0 = qv * kv0, p1 = qv * kv1, p2 = qv * kv2, p3 = qv * kv3;
            p0 += __shfl_xor(p0, 1); p1 += __shfl_xor(p1, 1);
            p2 += __shfl_xor(p2, 1); p3 += __shfl_xor(p3, 1);
            p0 += __shfl_xor(p0, 2); p1 += __shfl_xor(p1, 2);
            p2 += __shfl_xor(p2, 2); p3 += __shfl_xor(p3, 2);
            p0 += __shfl_xor(p0, 4); p1 += __shfl_xor(p1, 4);
            p2 += __shfl_xor(p2, 4); p3 += __shfl_xor(p3, 4);

            const float ex0 = __expf(p0 * 0.3535533905932738f);
            const float ex1 = __expf(p1 * 0.3535533905932738f);
            const float ex2 = __expf(p2 * 0.3535533905932738f);
            const float ex3 = __expf(p3 * 0.3535533905932738f);

            den += ex0; acc += ex0 * vv0;
            den += ex1; acc += ex1 * vv1;
            den += ex2; acc += ex2 * vv2;
            den += ex3; acc += ex3 * vv3;
        }
        for (; j < nj; ++j) {
            const int dn = __shfl(dn_lane, j);
            const float kv = k[(size_t)dn * OUT_FEATS + lane];
            const float vv = v[(size_t)dn * OUT_FEATS + lane];
            float p = qv * kv;
            p += __shfl_xor(p, 1);
            p += __shfl_xor(p, 2);
            p += __shfl_xor(p, 4);
            const float ex = __expf(p * 0.3535533905932738f);
            den += ex;
            acc += ex * vv;
        }
    }
    out[(size_t)node * OUT_FEATS + lane] = acc / (den + 1e-16f);
}

extern "C" void kernel_launch(void* const* d_in, const int* in_sizes, int n_in,
                              void* d_out, int out_size, void* d_ws, size_t ws_size,
                              hipStream_t stream)
{
    const float* x  = (const float*)d_in[0];
    const int*  edge = (const int*)d_in[1];
    const float* Wq = (const float*)d_in[2];
    const float* bq = (const float*)d_in[3];
    const float* Wk = (const float*)d_in[4];
    const float* bk = (const float*)d_in[5];
    const float* Wv = (const float*)d_in[6];
    const float* bv = (const float*)d_in[7];
    float* out = (float*)d_out;

    // Workspace: q | k | v | cnt | row_start | bsum | pos_e | csr_dst
    float* q  = (float*)d_ws;
    float* k  = q + (size_t)N_NODES * OUT_FEATS;
    float* v  = k + (size_t)N_NODES * OUT_FEATS;
    int* cnt       = (int*)(v + (size_t)N_NODES * OUT_FEATS);
    int* row_start = cnt + N_NODES;
    int* bsum      = row_start + N_NODES;
    int* pos_e     = bsum + 512;
    int* csr_dst   = pos_e + E_EDGES;

    const int* src = edge;            // edge[0]
    const int* dst = edge + E_EDGES;  // edge[1]

    hipMemsetAsync(cnt, 0, N_NODES * sizeof(int), stream);

    qkv_kernel<<<(N_NODES + 63) / 64, 256, 0, stream>>>(
        x, Wq, bq, Wk, bk, Wv, bv, q, k, v);

    const int eblocks = (E_EDGES + 255) / 256;
    hist_kernel<<<eblocks, 256, 0, stream>>>(src, cnt, pos_e);
    scan1_kernel<<<SCAN_BLOCKS, 256, 0, stream>>>(cnt, row_start, bsum);
    scan2_kernel<<<1, 512, 0, stream>>>(bsum);
    csr_scatter_kernel<<<eblocks, 256, 0, stream>>>(src, dst, row_start, bsum, pos_e, csr_dst);

    attn_kernel<<<N_NODES / 4, 256, 0, stream>>>(q, k, v, row_start, bsum, cnt, csr_dst, out);
}

// Round 4
// 317.630 us; speedup vs baseline: 9.9833x; 1.3265x over previous
//
#include <hip/hip_runtime.h>

#define N_NODES   100000
#define E_EDGES   1600000
#define IN_FEATS  128
#define OUT_FEATS 64
#define NH        8
#define DK        8

#define SCAN_BLOCKS ((N_NODES + 255) / 256)   // 391

typedef __attribute__((ext_vector_type(8))) short short8;
typedef __attribute__((ext_vector_type(4))) float floatx4;

__device__ __forceinline__ ushort f2bf(float f) {
    uint u = __float_as_uint(f);
    u += 0x7FFF + ((u >> 16) & 1);            // RNE
    return (ushort)(u >> 16);
}

// ---------------------------------------------------------------------------
// QKV projection via bf16 MFMA. Block: 64 node-rows; 4 waves, each a 16-row
// strip x 64 cols. LDS holds x-tile and one W at a time as bf16 [64][136]
// (pad 8 -> 2-way max bank aliasing on b128 frag reads, free on gfx950).
// Outputs: q fp32 [N][64]; kv packed bf16 pairs (k lo, v hi) as uint [N][64].
// ---------------------------------------------------------------------------
__device__ __forceinline__ void stage_w(const float* __restrict__ W,
                                        ushort wt[64][136], int t)
{
    for (int idx = t; idx < 64 * 32; idx += 256) {
        const int r  = idx >> 5;
        const int c4 = idx & 31;
        const float4 val = ((const float4*)(W + r * IN_FEATS))[c4];
        ushort4 s;
        s.x = f2bf(val.x); s.y = f2bf(val.y); s.z = f2bf(val.z); s.w = f2bf(val.w);
        *(ushort4*)&wt[r][c4 * 4] = s;
    }
}

__device__ __forceinline__ void compute_mat(
    const ushort xs[64][136], const ushort wt[64][136],
    const float* __restrict__ b, int w, int lm, int qd, floatx4 acc[4])
{
    #pragma unroll
    for (int nt = 0; nt < 4; ++nt) {
        const float bb = b[16 * nt + lm];
        acc[nt] = (floatx4){bb, bb, bb, bb};
    }
    #pragma unroll
    for (int kc = 0; kc < 4; ++kc) {
        const short8 a = *(const short8*)&xs[16 * w + lm][32 * kc + 8 * qd];
        #pragma unroll
        for (int nt = 0; nt < 4; ++nt) {
            const short8 bf = *(const short8*)&wt[16 * nt + lm][32 * kc + 8 * qd];
            acc[nt] = __builtin_amdgcn_mfma_f32_16x16x32_bf16(a, bf, acc[nt], 0, 0, 0);
        }
    }
}

__global__ __launch_bounds__(256) void qkv_kernel(
    const float* __restrict__ x,
    const float* __restrict__ Wq, const float* __restrict__ bq,
    const float* __restrict__ Wk, const float* __restrict__ bk,
    const float* __restrict__ Wv, const float* __restrict__ bv,
    float* __restrict__ qo, uint* __restrict__ kvo)
{
    __shared__ ushort xs[64][136];
    __shared__ ushort wt[64][136];

    const int t    = threadIdx.x;
    const int row0 = blockIdx.x * 64;

    // Stage x tile as bf16 (coalesced float4 reads).
    for (int idx = t; idx < 64 * 32; idx += 256) {
        const int r   = idx >> 5;
        const int c4  = idx & 31;
        const int row = row0 + r;
        float4 val = make_float4(0.f, 0.f, 0.f, 0.f);
        if (row < N_NODES)
            val = ((const float4*)(x + (size_t)row * IN_FEATS))[c4];
        ushort4 s;
        s.x = f2bf(val.x); s.y = f2bf(val.y); s.z = f2bf(val.z); s.w = f2bf(val.w);
        *(ushort4*)&xs[r][c4 * 4] = s;
    }

    const int lane = t & 63;
    const int w    = t >> 6;        // wave -> 16-row strip
    const int lm   = lane & 15;     // A row / B col / D col
    const int qd   = lane >> 4;     // quad: A k-base / D row-quad

    floatx4 acc[4], kacc[4];

    // ---- Q ----
    stage_w(Wq, wt, t);
    __syncthreads();
    compute_mat(xs, wt, bq, w, lm, qd, acc);
    #pragma unroll
    for (int nt = 0; nt < 4; ++nt) {
        #pragma unroll
        for (int reg = 0; reg < 4; ++reg) {
            const int row = row0 + 16 * w + 4 * qd + reg;
            if (row < N_NODES)
                qo[(size_t)row * OUT_FEATS + 16 * nt + lm] = acc[nt][reg];
        }
    }

    // ---- K (keep in registers) ----
    __syncthreads();
    stage_w(Wk, wt, t);
    __syncthreads();
    compute_mat(xs, wt, bk, w, lm, qd, kacc);

    // ---- V, then pack (k,v) as bf16 pair per element ----
    __syncthreads();
    stage_w(Wv, wt, t);
    __syncthreads();
    compute_mat(xs, wt, bv, w, lm, qd, acc);

    #pragma unroll
    for (int nt = 0; nt < 4; ++nt) {
        #pragma unroll
        for (int reg = 0; reg < 4; ++reg) {
            const int row = row0 + 16 * w + 4 * qd + reg;
            if (row < N_NODES) {
                const uint kb = f2bf(kacc[nt][reg]);
                const uint vb = f2bf(acc[nt][reg]);
                kvo[(size_t)row * OUT_FEATS + 16 * nt + lm] = kb | (vb << 16);
            }
        }
    }
}

// ---------------------------------------------------------------------------
// CSR build: histogram captures per-edge position -> scan -> atomic-free
// scatter. Block-offset add is folded into the consumers.
// ---------------------------------------------------------------------------
__global__ __launch_bounds__(256) void hist_kernel(
    const int* __restrict__ src, int* __restrict__ cnt, int* __restrict__ pos_e)
{
    const int e = blockIdx.x * 256 + threadIdx.x;
    if (e < E_EDGES) pos_e[e] = atomicAdd(&cnt[src[e]], 1);
}

__global__ __launch_bounds__(256) void scan1_kernel(
    const int* __restrict__ cnt, int* __restrict__ row_start,
    int* __restrict__ bsum)
{
    __shared__ int s[256];
    const int tid = threadIdx.x;
    const int i   = blockIdx.x * 256 + tid;
    const int v   = (i < N_NODES) ? cnt[i] : 0;
    int x = v;
    s[tid] = x;
    __syncthreads();
    for (int off = 1; off < 256; off <<= 1) {
        const int t = (tid >= off) ? s[tid - off] : 0;
        __syncthreads();
        x += t;
        s[tid] = x;
        __syncthreads();
    }
    if (i < N_NODES) row_start[i] = x - v;      // exclusive within block
    if (tid == 255)  bsum[blockIdx.x] = x;      // block total
}

__global__ __launch_bounds__(512) void scan2_kernel(int* __restrict__ bsum)
{
    __shared__ int s[512];
    const int tid = threadIdx.x;
    const int v   = (tid < SCAN_BLOCKS) ? bsum[tid] : 0;
    int x = v;
    s[tid] = x;
    __syncthreads();
    for (int off = 1; off < 512; off <<= 1) {
        const int t = (tid >= off) ? s[tid - off] : 0;
        __syncthreads();
        x += t;
        s[tid] = x;
        __syncthreads();
    }
    if (tid < SCAN_BLOCKS) bsum[tid] = x - v;   // exclusive block offsets
}

__global__ __launch_bounds__(256) void csr_scatter_kernel(
    const int* __restrict__ src, const int* __restrict__ dst,
    const int* __restrict__ row_start, const int* __restrict__ bsum,
    const int* __restrict__ pos_e, int* __restrict__ csr_dst)
{
    const int e = blockIdx.x * 256 + threadIdx.x;
    if (e >= E_EDGES) return;
    const int s = src[e];
    csr_dst[row_start[s] + bsum[s >> 8] + pos_e[e]] = dst[e];
}

// ---------------------------------------------------------------------------
// Fused attention: one wave per node; lane = h*8+d owns out column `lane`.
// kv row is packed bf16 (k lo / v hi): ONE uint load per edge per lane.
// Indices prefetched 64-at-a-time, unroll x4 for MLP.
// ---------------------------------------------------------------------------
__global__ __launch_bounds__(256) void attn_kernel(
    const float* __restrict__ q, const uint* __restrict__ kv,
    const int* __restrict__ row_start, const int* __restrict__ bsum,
    const int* __restrict__ cnt,
    const int* __restrict__ csr_dst, float* __restrict__ out)
{
    const int lane = threadIdx.x & 63;
    const int wv   = threadIdx.x >> 6;
    const int node = blockIdx.x * 4 + wv;     // grid = N/4 exactly

    const float qv    = q[(size_t)node * OUT_FEATS + lane];
    const int   start = row_start[node] + bsum[node >> 8];
    const int   deg   = cnt[node];

    float den = 0.f, acc = 0.f;
    for (int base = 0; base < deg; base += 64) {
        const int rem = deg - base;
        const int nj  = rem < 64 ? rem : 64;
        int dn_lane = 0;
        if (lane < nj) dn_lane = csr_dst[start + base + lane];

        int j = 0;
        for (; j + 4 <= nj; j += 4) {
            const int dn0 = __shfl(dn_lane, j + 0);
            const int dn1 = __shfl(dn_lane, j + 1);
            const int dn2 = __shfl(dn_lane, j + 2);
            const int dn3 = __shfl(dn_lane, j + 3);
            const uint u0 = kv[(size_t)dn0 * OUT_FEATS + lane];
            const uint u1 = kv[(size_t)dn1 * OUT_FEATS + lane];
            const uint u2 = kv[(size_t)dn2 * OUT_FEATS + lane];
            const uint u3 = kv[(size_t)dn3 * OUT_FEATS + lane];

            float p0 = qv * __uint_as_float(u0 << 16);
            float p1 = qv * __uint_as_float(u1 << 16);
            float p2 = qv * __uint_as_float(u2 << 16);
            float p3 = qv * __uint_as_float(u3 << 16);
            p0 += __shfl_xor(p0, 1); p1 += __shfl_xor(p1, 1);
            p2 += __shfl_xor(p2, 1); p3 += __shfl_xor(p3, 1);
            p0 += __shfl_xor(p0, 2); p1 += __shfl_xor(p1, 2);
            p2 += __shfl_xor(p2, 2); p3 += __shfl_xor(p3, 2);
            p0 += __shfl_xor(p0, 4); p1 += __shfl_xor(p1, 4);
            p2 += __shfl_xor(p2, 4); p3 += __shfl_xor(p3, 4);

            const float ex0 = __expf(p0 * 0.3535533905932738f);
            const float ex1 = __expf(p1 * 0.3535533905932738f);
            const float ex2 = __expf(p2 * 0.3535533905932738f);
            const float ex3 = __expf(p3 * 0.3535533905932738f);

            den += ex0; acc += ex0 * __uint_as_float(u0 & 0xFFFF0000u);
            den += ex1; acc += ex1 * __uint_as_float(u1 & 0xFFFF0000u);
            den += ex2; acc += ex2 * __uint_as_float(u2 & 0xFFFF0000u);
            den += ex3; acc += ex3 * __uint_as_float(u3 & 0xFFFF0000u);
        }
        for (; j < nj; ++j) {
            const int dn = __shfl(dn_lane, j);
            const uint u = kv[(size_t)dn * OUT_FEATS + lane];
            float p = qv * __uint_as_float(u << 16);
            p += __shfl_xor(p, 1);
            p += __shfl_xor(p, 2);
            p += __shfl_xor(p, 4);
            const float ex = __expf(p * 0.3535533905932738f);
            den += ex;
            acc += ex * __uint_as_float(u & 0xFFFF0000u);
        }
    }
    out[(size_t)node * OUT_FEATS + lane] = acc / (den + 1e-16f);
}

extern "C" void kernel_launch(void* const* d_in, const int* in_sizes, int n_in,
                              void* d_out, int out_size, void* d_ws, size_t ws_size,
                              hipStream_t stream)
{
    const float* x  = (const float*)d_in[0];
    const int*  edge = (const int*)d_in[1];
    const float* Wq = (const float*)d_in[2];
    const float* bq = (const float*)d_in[3];
    const float* Wk = (const float*)d_in[4];
    const float* bk = (const float*)d_in[5];
    const float* Wv = (const float*)d_in[6];
    const float* bv = (const float*)d_in[7];
    float* out = (float*)d_out;

    // Workspace: q(f32) | kv(packed u32) | cnt | row_start | bsum | pos_e | csr_dst
    float* q  = (float*)d_ws;
    uint*  kv = (uint*)(q + (size_t)N_NODES * OUT_FEATS);
    int* cnt       = (int*)(kv + (size_t)N_NODES * OUT_FEATS);
    int* row_start = cnt + N_NODES;
    int* bsum      = row_start + N_NODES;
    int* pos_e     = bsum + 512;
    int* csr_dst   = pos_e + E_EDGES;

    const int* src = edge;            // edge[0]
    const int* dst = edge + E_EDGES;  // edge[1]

    hipMemsetAsync(cnt, 0, N_NODES * sizeof(int), stream);

    qkv_kernel<<<(N_NODES + 63) / 64, 256, 0, stream>>>(
        x, Wq, bq, Wk, bk, Wv, bv, q, kv);

    const int eblocks = (E_EDGES + 255) / 256;
    hist_kernel<<<eblocks, 256, 0, stream>>>(src, cnt, pos_e);
    scan1_kernel<<<SCAN_BLOCKS, 256, 0, stream>>>(cnt, row_start, bsum);
    scan2_kernel<<<1, 512, 0, stream>>>(bsum);
    csr_scatter_kernel<<<eblocks, 256, 0, stream>>>(src, dst, row_start, bsum, pos_e, csr_dst);

    attn_kernel<<<N_NODES / 4, 256, 0, stream>>>(q, kv, row_start, bsum, cnt, csr_dst, out);
}

// Round 5
// 306.469 us; speedup vs baseline: 10.3469x; 1.0364x over previous
//
#include <hip/hip_runtime.h>

#define N_NODES   100000
#define E_EDGES   1600000
#define IN_FEATS  128
#define OUT_FEATS 64
#define NH        8
#define DK        8

#define SCAN_BLOCKS ((N_NODES + 255) / 256)   // 391

typedef __attribute__((ext_vector_type(8))) short short8;
typedef __attribute__((ext_vector_type(4))) float floatx4;

__device__ __forceinline__ ushort f2bf(float f) {
    uint u = __float_as_uint(f);
    u += 0x7FFF + ((u >> 16) & 1);            // RNE
    return (ushort)(u >> 16);
}
__device__ __forceinline__ float bflo(uint u) { return __uint_as_float(u << 16); }
__device__ __forceinline__ float bfhi(uint u) { return __uint_as_float(u & 0xFFFF0000u); }

// ---------------------------------------------------------------------------
// QKV projection via bf16 MFMA (unchanged from R4).
// ---------------------------------------------------------------------------
__device__ __forceinline__ void stage_w(const float* __restrict__ W,
                                        ushort wt[64][136], int t)
{
    for (int idx = t; idx < 64 * 32; idx += 256) {
        const int r  = idx >> 5;
        const int c4 = idx & 31;
        const float4 val = ((const float4*)(W + r * IN_FEATS))[c4];
        ushort4 s;
        s.x = f2bf(val.x); s.y = f2bf(val.y); s.z = f2bf(val.z); s.w = f2bf(val.w);
        *(ushort4*)&wt[r][c4 * 4] = s;
    }
}

__device__ __forceinline__ void compute_mat(
    const ushort xs[64][136], const ushort wt[64][136],
    const float* __restrict__ b, int w, int lm, int qd, floatx4 acc[4])
{
    #pragma unroll
    for (int nt = 0; nt < 4; ++nt) {
        const float bb = b[16 * nt + lm];
        acc[nt] = (floatx4){bb, bb, bb, bb};
    }
    #pragma unroll
    for (int kc = 0; kc < 4; ++kc) {
        const short8 a = *(const short8*)&xs[16 * w + lm][32 * kc + 8 * qd];
        #pragma unroll
        for (int nt = 0; nt < 4; ++nt) {
            const short8 bf = *(const short8*)&wt[16 * nt + lm][32 * kc + 8 * qd];
            acc[nt] = __builtin_amdgcn_mfma_f32_16x16x32_bf16(a, bf, acc[nt], 0, 0, 0);
        }
    }
}

__global__ __launch_bounds__(256) void qkv_kernel(
    const float* __restrict__ x,
    const float* __restrict__ Wq, const float* __restrict__ bq,
    const float* __restrict__ Wk, const float* __restrict__ bk,
    const float* __restrict__ Wv, const float* __restrict__ bv,
    float* __restrict__ qo, uint* __restrict__ kvo)
{
    __shared__ ushort xs[64][136];
    __shared__ ushort wt[64][136];

    const int t    = threadIdx.x;
    const int row0 = blockIdx.x * 64;

    for (int idx = t; idx < 64 * 32; idx += 256) {
        const int r   = idx >> 5;
        const int c4  = idx & 31;
        const int row = row0 + r;
        float4 val = make_float4(0.f, 0.f, 0.f, 0.f);
        if (row < N_NODES)
            val = ((const float4*)(x + (size_t)row * IN_FEATS))[c4];
        ushort4 s;
        s.x = f2bf(val.x); s.y = f2bf(val.y); s.z = f2bf(val.z); s.w = f2bf(val.w);
        *(ushort4*)&xs[r][c4 * 4] = s;
    }

    const int lane = t & 63;
    const int w    = t >> 6;
    const int lm   = lane & 15;
    const int qd   = lane >> 4;

    floatx4 acc[4], kacc[4];

    stage_w(Wq, wt, t);
    __syncthreads();
    compute_mat(xs, wt, bq, w, lm, qd, acc);
    #pragma unroll
    for (int nt = 0; nt < 4; ++nt) {
        #pragma unroll
        for (int reg = 0; reg < 4; ++reg) {
            const int row = row0 + 16 * w + 4 * qd + reg;
            if (row < N_NODES)
                qo[(size_t)row * OUT_FEATS + 16 * nt + lm] = acc[nt][reg];
        }
    }

    __syncthreads();
    stage_w(Wk, wt, t);
    __syncthreads();
    compute_mat(xs, wt, bk, w, lm, qd, kacc);

    __syncthreads();
    stage_w(Wv, wt, t);
    __syncthreads();
    compute_mat(xs, wt, bv, w, lm, qd, acc);

    #pragma unroll
    for (int nt = 0; nt < 4; ++nt) {
        #pragma unroll
        for (int reg = 0; reg < 4; ++reg) {
            const int row = row0 + 16 * w + 4 * qd + reg;
            if (row < N_NODES) {
                const uint kb = f2bf(kacc[nt][reg]);
                const uint vb = f2bf(acc[nt][reg]);
                kvo[(size_t)row * OUT_FEATS + 16 * nt + lm] = kb | (vb << 16);
            }
        }
    }
}

// ---------------------------------------------------------------------------
// CSR build (x4-vectorized edge reads).
// ---------------------------------------------------------------------------
__global__ __launch_bounds__(256) void hist_kernel(
    const int* __restrict__ src, int* __restrict__ cnt, int* __restrict__ pos_e)
{
    const int i = blockIdx.x * 256 + threadIdx.x;
    if (i >= E_EDGES / 4) return;
    const int4 s4 = ((const int4*)src)[i];
    int4 p4;
    p4.x = atomicAdd(&cnt[s4.x], 1);
    p4.y = atomicAdd(&cnt[s4.y], 1);
    p4.z = atomicAdd(&cnt[s4.z], 1);
    p4.w = atomicAdd(&cnt[s4.w], 1);
    ((int4*)pos_e)[i] = p4;
}

__global__ __launch_bounds__(256) void scan1_kernel(
    const int* __restrict__ cnt, int* __restrict__ row_start,
    int* __restrict__ bsum)
{
    __shared__ int s[256];
    const int tid = threadIdx.x;
    const int i   = blockIdx.x * 256 + tid;
    const int v   = (i < N_NODES) ? cnt[i] : 0;
    int x = v;
    s[tid] = x;
    __syncthreads();
    for (int off = 1; off < 256; off <<= 1) {
        const int t = (tid >= off) ? s[tid - off] : 0;
        __syncthreads();
        x += t;
        s[tid] = x;
        __syncthreads();
    }
    if (i < N_NODES) row_start[i] = x - v;
    if (tid == 255)  bsum[blockIdx.x] = x;
}

__global__ __launch_bounds__(512) void scan2_kernel(int* __restrict__ bsum)
{
    __shared__ int s[512];
    const int tid = threadIdx.x;
    const int v   = (tid < SCAN_BLOCKS) ? bsum[tid] : 0;
    int x = v;
    s[tid] = x;
    __syncthreads();
    for (int off = 1; off < 512; off <<= 1) {
        const int t = (tid >= off) ? s[tid - off] : 0;
        __syncthreads();
        x += t;
        s[tid] = x;
        __syncthreads();
    }
    if (tid < SCAN_BLOCKS) bsum[tid] = x - v;
}

__global__ __launch_bounds__(256) void csr_scatter_kernel(
    const int* __restrict__ src, const int* __restrict__ dst,
    const int* __restrict__ row_start, const int* __restrict__ bsum,
    const int* __restrict__ pos_e, int* __restrict__ csr_dst)
{
    const int i = blockIdx.x * 256 + threadIdx.x;
    if (i >= E_EDGES / 4) return;
    const int4 s4 = ((const int4*)src)[i];
    const int4 d4 = ((const int4*)dst)[i];
    const int4 p4 = ((const int4*)pos_e)[i];
    csr_dst[row_start[s4.x] + bsum[s4.x >> 8] + p4.x] = d4.x;
    csr_dst[row_start[s4.y] + bsum[s4.y >> 8] + p4.y] = d4.y;
    csr_dst[row_start[s4.z] + bsum[s4.z >> 8] + p4.z] = d4.z;
    csr_dst[row_start[s4.w] + bsum[s4.w >> 8] + p4.w] = d4.w;
}

// ---------------------------------------------------------------------------
// Fused attention, register-dot variant. One wave per node.
// Lane l = h*8 + j: scores edge-slot j (of each 8-edge group) for head h.
// Per group: 1 bpermute (dn), 2 dwordx4 kv loads, in-register 8-dot,
// ONE exp per (edge,head), 8 local acc FMAs. No per-edge shuffles.
// Final: butterfly-reduce over the 3 j-bits once per node; lane h*8+j then
// owns output column h*8+j.
// ---------------------------------------------------------------------------
__global__ __launch_bounds__(256) void attn_kernel(
    const float* __restrict__ q, const uint* __restrict__ kv,
    const int* __restrict__ row_start, const int* __restrict__ bsum,
    const int* __restrict__ cnt,
    const int* __restrict__ csr_dst, float* __restrict__ out)
{
    const int lane = threadIdx.x & 63;
    const int wv   = threadIdx.x >> 6;
    const int node = blockIdx.x * 4 + wv;     // grid = N/4 exactly
    const int h    = lane >> 3;               // head
    const int jme  = lane & 7;                // edge-slot within group

    const float4* qrow = (const float4*)(q + (size_t)node * OUT_FEATS + h * DK);
    const float4 qa = qrow[0];
    const float4 qb = qrow[1];

    const int start = row_start[node] + bsum[node >> 8];
    const int deg   = cnt[node];

    float den = 0.f;
    float a0 = 0.f, a1 = 0.f, a2 = 0.f, a3 = 0.f;
    float a4 = 0.f, a5 = 0.f, a6 = 0.f, a7 = 0.f;

    for (int base = 0; base < deg; base += 64) {
        const int rem = deg - base;
        const int nj  = rem < 64 ? rem : 64;
        int dn_lane = 0;
        if (lane < nj) dn_lane = csr_dst[start + base + lane];

        for (int g = 0; g < nj; g += 8) {
            const int dn = __shfl(dn_lane, g + jme);     // 0 for invalid slots
            const uint4* kvp = (const uint4*)(kv + (size_t)dn * OUT_FEATS + h * DK);
            const uint4 ua = kvp[0];
            const uint4 ub = kvp[1];

            float p = qa.x * bflo(ua.x) + qa.y * bflo(ua.y) +
                      qa.z * bflo(ua.z) + qa.w * bflo(ua.w) +
                      qb.x * bflo(ub.x) + qb.y * bflo(ub.y) +
                      qb.z * bflo(ub.z) + qb.w * bflo(ub.w);
            // exp(p/sqrt(8)) = 2^(p * 0.51006971)
            float ex = exp2f(p * 0.51006971413f);
            if (g + jme >= nj) ex = 0.f;                 // tail slots contribute 0

            den += ex;
            a0 += ex * bfhi(ua.x); a1 += ex * bfhi(ua.y);
            a2 += ex * bfhi(ua.z); a3 += ex * bfhi(ua.w);
            a4 += ex * bfhi(ub.x); a5 += ex * bfhi(ub.y);
            a6 += ex * bfhi(ub.z); a7 += ex * bfhi(ub.w);
        }
    }

    // Reduce partials across the 8 j-lanes of this head group (once per node).
    #pragma unroll
    for (int m = 1; m <= 4; m <<= 1) {
        den += __shfl_xor(den, m);
        a0 += __shfl_xor(a0, m); a1 += __shfl_xor(a1, m);
        a2 += __shfl_xor(a2, m); a3 += __shfl_xor(a3, m);
        a4 += __shfl_xor(a4, m); a5 += __shfl_xor(a5, m);
        a6 += __shfl_xor(a6, m); a7 += __shfl_xor(a7, m);
    }

    // Lane h*8+jme owns output column h*8+jme -> select a[jme].
    float r = a0;
    r = (jme == 1) ? a1 : r;
    r = (jme == 2) ? a2 : r;
    r = (jme == 3) ? a3 : r;
    r = (jme == 4) ? a4 : r;
    r = (jme == 5) ? a5 : r;
    r = (jme == 6) ? a6 : r;
    r = (jme == 7) ? a7 : r;

    out[(size_t)node * OUT_FEATS + lane] = r / (den + 1e-16f);
}

extern "C" void kernel_launch(void* const* d_in, const int* in_sizes, int n_in,
                              void* d_out, int out_size, void* d_ws, size_t ws_size,
                              hipStream_t stream)
{
    const float* x  = (const float*)d_in[0];
    const int*  edge = (const int*)d_in[1];
    const float* Wq = (const float*)d_in[2];
    const float* bq = (const float*)d_in[3];
    const float* Wk = (const float*)d_in[4];
    const float* bk = (const float*)d_in[5];
    const float* Wv = (const float*)d_in[6];
    const float* bv = (const float*)d_in[7];
    float* out = (float*)d_out;

    // Workspace: q(f32) | kv(packed u32) | cnt | row_start | bsum | pos_e | csr_dst
    float* q  = (float*)d_ws;
    uint*  kv = (uint*)(q + (size_t)N_NODES * OUT_FEATS);
    int* cnt       = (int*)(kv + (size_t)N_NODES * OUT_FEATS);
    int* row_start = cnt + N_NODES;
    int* bsum      = row_start + N_NODES;
    int* pos_e     = bsum + 512;
    int* csr_dst   = pos_e + E_EDGES;

    const int* src = edge;            // edge[0]
    const int* dst = edge + E_EDGES;  // edge[1]

    hipMemsetAsync(cnt, 0, N_NODES * sizeof(int), stream);

    qkv_kernel<<<(N_NODES + 63) / 64, 256, 0, stream>>>(
        x, Wq, bq, Wk, bk, Wv, bv, q, kv);

    const int e4blocks = (E_EDGES / 4 + 255) / 256;
    hist_kernel<<<e4blocks, 256, 0, stream>>>(src, cnt, pos_e);
    scan1_kernel<<<SCAN_BLOCKS, 256, 0, stream>>>(cnt, row_start, bsum);
    scan2_kernel<<<1, 512, 0, stream>>>(bsum);
    csr_scatter_kernel<<<e4blocks, 256, 0, stream>>>(src, dst, row_start, bsum, pos_e, csr_dst);

    attn_kernel<<<N_NODES / 4, 256, 0, stream>>>(q, kv, row_start, bsum, cnt, csr_dst, out);
}

// Round 6
// 299.727 us; speedup vs baseline: 10.5797x; 1.0225x over previous
//
#include <hip/hip_runtime.h>

#define N_NODES   100000
#define E_EDGES   1600000
#define IN_FEATS  128
#define OUT_FEATS 64
#define NH        8
#define DK        8

#define QKV_BLOCKS   1563          // ceil(N/64)
#define HIST_BLOCKS  1563          // ceil((E/4)/256)
#define N4           (N_NODES / 4) // 25000 int4 elements of cnt
#define SCAN1_BLOCKS ((N4 + 255) / 256)   // 98

typedef __attribute__((ext_vector_type(8))) short short8;
typedef __attribute__((ext_vector_type(4))) float floatx4;

__device__ __forceinline__ ushort f2bf(float f) {
    uint u = __float_as_uint(f);
    u += 0x7FFF + ((u >> 16) & 1);            // RNE
    return (ushort)(u >> 16);
}
__device__ __forceinline__ float bflo(uint u) { return __uint_as_float(u << 16); }
__device__ __forceinline__ float bfhi(uint u) { return __uint_as_float(u & 0xFFFF0000u); }

// ---------------------------------------------------------------------------
// Fused QKV projection (bf16 MFMA) + degree histogram.
// Blocks [0, QKV_BLOCKS): 64-row QKV tile. Blocks [QKV_BLOCKS, +HIST_BLOCKS):
// x4-vectorized histogram with per-edge position capture (ushort).
// ---------------------------------------------------------------------------
__device__ __forceinline__ void stage_w(const float* __restrict__ W,
                                        ushort wt[64][136], int t)
{
    for (int idx = t; idx < 64 * 32; idx += 256) {
        const int r  = idx >> 5;
        const int c4 = idx & 31;
        const float4 val = ((const float4*)(W + r * IN_FEATS))[c4];
        ushort4 s;
        s.x = f2bf(val.x); s.y = f2bf(val.y); s.z = f2bf(val.z); s.w = f2bf(val.w);
        *(ushort4*)&wt[r][c4 * 4] = s;
    }
}

__device__ __forceinline__ void compute_mat(
    const ushort xs[64][136], const ushort wt[64][136],
    const float* __restrict__ b, int w, int lm, int qd, floatx4 acc[4])
{
    #pragma unroll
    for (int nt = 0; nt < 4; ++nt) {
        const float bb = b[16 * nt + lm];
        acc[nt] = (floatx4){bb, bb, bb, bb};
    }
    #pragma unroll
    for (int kc = 0; kc < 4; ++kc) {
        const short8 a = *(const short8*)&xs[16 * w + lm][32 * kc + 8 * qd];
        #pragma unroll
        for (int nt = 0; nt < 4; ++nt) {
            const short8 bf = *(const short8*)&wt[16 * nt + lm][32 * kc + 8 * qd];
            acc[nt] = __builtin_amdgcn_mfma_f32_16x16x32_bf16(a, bf, acc[nt], 0, 0, 0);
        }
    }
}

__global__ __launch_bounds__(256) void qkv_hist_kernel(
    const float* __restrict__ x,
    const float* __restrict__ Wq, const float* __restrict__ bq,
    const float* __restrict__ Wk, const float* __restrict__ bk,
    const float* __restrict__ Wv, const float* __restrict__ bv,
    float* __restrict__ qo, uint* __restrict__ kvo,
    const int* __restrict__ src, int* __restrict__ cnt,
    ushort* __restrict__ pos_e)
{
    __shared__ ushort xs[64][136];
    __shared__ ushort wt[64][136];

    if (blockIdx.x >= QKV_BLOCKS) {
        // ---- histogram branch ----
        const int i = (blockIdx.x - QKV_BLOCKS) * 256 + threadIdx.x;
        if (i < E_EDGES / 4) {
            const int4 s4 = ((const int4*)src)[i];
            ushort4 p4;
            p4.x = (ushort)atomicAdd(&cnt[s4.x], 1);
            p4.y = (ushort)atomicAdd(&cnt[s4.y], 1);
            p4.z = (ushort)atomicAdd(&cnt[s4.z], 1);
            p4.w = (ushort)atomicAdd(&cnt[s4.w], 1);
            ((ushort4*)pos_e)[i] = p4;
        }
        return;
    }

    const int t    = threadIdx.x;
    const int row0 = blockIdx.x * 64;

    for (int idx = t; idx < 64 * 32; idx += 256) {
        const int r   = idx >> 5;
        const int c4  = idx & 31;
        const int row = row0 + r;
        float4 val = make_float4(0.f, 0.f, 0.f, 0.f);
        if (row < N_NODES)
            val = ((const float4*)(x + (size_t)row * IN_FEATS))[c4];
        ushort4 s;
        s.x = f2bf(val.x); s.y = f2bf(val.y); s.z = f2bf(val.z); s.w = f2bf(val.w);
        *(ushort4*)&xs[r][c4 * 4] = s;
    }

    const int lane = t & 63;
    const int w    = t >> 6;
    const int lm   = lane & 15;
    const int qd   = lane >> 4;

    floatx4 acc[4], kacc[4];

    stage_w(Wq, wt, t);
    __syncthreads();
    compute_mat(xs, wt, bq, w, lm, qd, acc);
    #pragma unroll
    for (int nt = 0; nt < 4; ++nt) {
        #pragma unroll
        for (int reg = 0; reg < 4; ++reg) {
            const int row = row0 + 16 * w + 4 * qd + reg;
            if (row < N_NODES)
                qo[(size_t)row * OUT_FEATS + 16 * nt + lm] = acc[nt][reg];
        }
    }

    __syncthreads();
    stage_w(Wk, wt, t);
    __syncthreads();
    compute_mat(xs, wt, bk, w, lm, qd, kacc);

    __syncthreads();
    stage_w(Wv, wt, t);
    __syncthreads();
    compute_mat(xs, wt, bv, w, lm, qd, acc);

    #pragma unroll
    for (int nt = 0; nt < 4; ++nt) {
        #pragma unroll
        for (int reg = 0; reg < 4; ++reg) {
            const int row = row0 + 16 * w + 4 * qd + reg;
            if (row < N_NODES) {
                const uint kb = f2bf(kacc[nt][reg]);
                const uint vb = f2bf(acc[nt][reg]);
                kvo[(size_t)row * OUT_FEATS + 16 * nt + lm] = kb | (vb << 16);
            }
        }
    }
}

// ---------------------------------------------------------------------------
// Scan 1: 1024 elements per block (int4/thread), wave-shfl scan, 1 barrier.
// row_start gets block-local exclusive prefix; bsum[b] = block total.
// ---------------------------------------------------------------------------
__global__ __launch_bounds__(256) void scan1_kernel(
    const int* __restrict__ cnt, int* __restrict__ row_start,
    int* __restrict__ bsum)
{
    __shared__ int wsum[4];
    const int tid  = threadIdx.x;
    const int lane = tid & 63;
    const int wv   = tid >> 6;
    const int idx  = blockIdx.x * 256 + tid;     // int4 index

    int4 v = make_int4(0, 0, 0, 0);
    if (idx < N4) v = ((const int4*)cnt)[idx];
    const int s = v.x + v.y + v.z + v.w;

    int sc = s;                                   // inclusive wave scan
    #pragma unroll
    for (int off = 1; off < 64; off <<= 1) {
        const int tt = __shfl_up(sc, off);
        if (lane >= off) sc += tt;
    }
    if (lane == 63) wsum[wv] = sc;
    __syncthreads();

    int woff = 0;
    #pragma unroll
    for (int i = 0; i < 3; ++i) woff += (i < wv) ? wsum[i] : 0;

    const int excl = woff + sc - s;
    if (idx < N4) {
        int4 r;
        r.x = excl;
        r.y = excl + v.x;
        r.z = r.y + v.y;
        r.w = r.z + v.z;
        ((int4*)row_start)[idx] = r;
    }
    if (tid == 255) bsum[blockIdx.x] = woff + sc;
}

// ---------------------------------------------------------------------------
// Scan 2: exclusive scan of the 98 block totals; single block, 2 waves.
// ---------------------------------------------------------------------------
__global__ __launch_bounds__(128) void scan2_kernel(int* __restrict__ bsum)
{
    __shared__ int wsum[2];
    const int tid  = threadIdx.x;
    const int lane = tid & 63;
    const int wv   = tid >> 6;

    const int v = (tid < SCAN1_BLOCKS) ? bsum[tid] : 0;
    int sc = v;
    #pragma unroll
    for (int off = 1; off < 64; off <<= 1) {
        const int tt = __shfl_up(sc, off);
        if (lane >= off) sc += tt;
    }
    if (lane == 63) wsum[wv] = sc;
    __syncthreads();
    const int woff = (wv == 1) ? wsum[0] : 0;
    if (tid < SCAN1_BLOCKS) bsum[tid] = woff + sc - v;
}

// ---------------------------------------------------------------------------
// CSR scatter (atomic-free): slot = row_start[s] + bsum[s>>10] + pos_e[e].
// ---------------------------------------------------------------------------
__global__ __launch_bounds__(256) void csr_scatter_kernel(
    const int* __restrict__ src, const int* __restrict__ dst,
    const int* __restrict__ row_start, const int* __restrict__ bsum,
    const ushort* __restrict__ pos_e, int* __restrict__ csr_dst)
{
    const int i = blockIdx.x * 256 + threadIdx.x;
    if (i >= E_EDGES / 4) return;
    const int4    s4 = ((const int4*)src)[i];
    const int4    d4 = ((const int4*)dst)[i];
    const ushort4 p4 = ((const ushort4*)pos_e)[i];
    csr_dst[row_start[s4.x] + bsum[s4.x >> 10] + p4.x] = d4.x;
    csr_dst[row_start[s4.y] + bsum[s4.y >> 10] + p4.y] = d4.y;
    csr_dst[row_start[s4.z] + bsum[s4.z >> 10] + p4.z] = d4.z;
    csr_dst[row_start[s4.w] + bsum[s4.w >> 10] + p4.w] = d4.w;
}

// ---------------------------------------------------------------------------
// Fused attention, register-dot, group loop unrolled x2 (16 edges/iter ->
// 4 independent dwordx4 gathers in flight per lane).
// ---------------------------------------------------------------------------
__global__ __launch_bounds__(256) void attn_kernel(
    const float* __restrict__ q, const uint* __restrict__ kv,
    const int* __restrict__ row_start, const int* __restrict__ bsum,
    const int* __restrict__ cnt,
    const int* __restrict__ csr_dst, float* __restrict__ out)
{
    const int lane = threadIdx.x & 63;
    const int wv   = threadIdx.x >> 6;
    const int node = blockIdx.x * 4 + wv;     // grid = N/4 exactly
    const int h    = lane >> 3;               // head
    const int jme  = lane & 7;                // edge-slot within group

    const float4* qrow = (const float4*)(q + (size_t)node * OUT_FEATS + h * DK);
    const float4 qa = qrow[0];
    const float4 qb = qrow[1];

    const int start = row_start[node] + bsum[node >> 10];
    const int deg   = cnt[node];

    float den = 0.f;
    float a0 = 0.f, a1 = 0.f, a2 = 0.f, a3 = 0.f;
    float a4 = 0.f, a5 = 0.f, a6 = 0.f, a7 = 0.f;

    for (int base = 0; base < deg; base += 64) {
        const int rem = deg - base;
        const int nj  = rem < 64 ? rem : 64;
        int dn_lane = 0;
        if (lane < nj) dn_lane = csr_dst[start + base + lane];

        int g = 0;
        for (; g + 16 <= nj; g += 16) {          // both groups fully valid
            const int dnA = __shfl(dn_lane, g + jme);
            const int dnB = __shfl(dn_lane, g + 8 + jme);
            const uint4* kpA = (const uint4*)(kv + (size_t)dnA * OUT_FEATS + h * DK);
            const uint4* kpB = (const uint4*)(kv + (size_t)dnB * OUT_FEATS + h * DK);
            const uint4 uaA = kpA[0];
            const uint4 ubA = kpA[1];
            const uint4 uaB = kpB[0];
            const uint4 ubB = kpB[1];

            float pA = qa.x * bflo(uaA.x) + qa.y * bflo(uaA.y) +
                       qa.z * bflo(uaA.z) + qa.w * bflo(uaA.w) +
                       qb.x * bflo(ubA.x) + qb.y * bflo(ubA.y) +
                       qb.z * bflo(ubA.z) + qb.w * bflo(ubA.w);
            float pB = qa.x * bflo(uaB.x) + qa.y * bflo(uaB.y) +
                       qa.z * bflo(uaB.z) + qa.w * bflo(uaB.w) +
                       qb.x * bflo(ubB.x) + qb.y * bflo(ubB.y) +
                       qb.z * bflo(ubB.z) + qb.w * bflo(ubB.w);
            const float exA = exp2f(pA * 0.51006971413f);   // log2(e)/sqrt(8)
            const float exB = exp2f(pB * 0.51006971413f);

            den += exA;
            a0 += exA * bfhi(uaA.x); a1 += exA * bfhi(uaA.y);
            a2 += exA * bfhi(uaA.z); a3 += exA * bfhi(uaA.w);
            a4 += exA * bfhi(ubA.x); a5 += exA * bfhi(ubA.y);
            a6 += exA * bfhi(ubA.z); a7 += exA * bfhi(ubA.w);
            den += exB;
            a0 += exB * bfhi(uaB.x); a1 += exB * bfhi(uaB.y);
            a2 += exB * bfhi(uaB.z); a3 += exB * bfhi(uaB.w);
            a4 += exB * bfhi(ubB.x); a5 += exB * bfhi(ubB.y);
            a6 += exB * bfhi(ubB.z); a7 += exB * bfhi(ubB.w);
        }
        for (; g < nj; g += 8) {                 // tail group(s), masked
            const int dn = __shfl(dn_lane, g + jme);
            const uint4* kvp = (const uint4*)(kv + (size_t)dn * OUT_FEATS + h * DK);
            const uint4 ua = kvp[0];
            const uint4 ub = kvp[1];

            float p = qa.x * bflo(ua.x) + qa.y * bflo(ua.y) +
                      qa.z * bflo(ua.z) + qa.w * bflo(ua.w) +
                      qb.x * bflo(ub.x) + qb.y * bflo(ub.y) +
                      qb.z * bflo(ub.z) + qb.w * bflo(ub.w);
            float ex = exp2f(p * 0.51006971413f);
            if (g + jme >= nj) ex = 0.f;

            den += ex;
            a0 += ex * bfhi(ua.x); a1 += ex * bfhi(ua.y);
            a2 += ex * bfhi(ua.z); a3 += ex * bfhi(ua.w);
            a4 += ex * bfhi(ub.x); a5 += ex * bfhi(ub.y);
            a6 += ex * bfhi(ub.z); a7 += ex * bfhi(ub.w);
        }
    }

    #pragma unroll
    for (int m = 1; m <= 4; m <<= 1) {
        den += __shfl_xor(den, m);
        a0 += __shfl_xor(a0, m); a1 += __shfl_xor(a1, m);
        a2 += __shfl_xor(a2, m); a3 += __shfl_xor(a3, m);
        a4 += __shfl_xor(a4, m); a5 += __shfl_xor(a5, m);
        a6 += __shfl_xor(a6, m); a7 += __shfl_xor(a7, m);
    }

    float r = a0;
    r = (jme == 1) ? a1 : r;
    r = (jme == 2) ? a2 : r;
    r = (jme == 3) ? a3 : r;
    r = (jme == 4) ? a4 : r;
    r = (jme == 5) ? a5 : r;
    r = (jme == 6) ? a6 : r;
    r = (jme == 7) ? a7 : r;

    out[(size_t)node * OUT_FEATS + lane] = r / (den + 1e-16f);
}

extern "C" void kernel_launch(void* const* d_in, const int* in_sizes, int n_in,
                              void* d_out, int out_size, void* d_ws, size_t ws_size,
                              hipStream_t stream)
{
    const float* x  = (const float*)d_in[0];
    const int*  edge = (const int*)d_in[1];
    const float* Wq = (const float*)d_in[2];
    const float* bq = (const float*)d_in[3];
    const float* Wk = (const float*)d_in[4];
    const float* bk = (const float*)d_in[5];
    const float* Wv = (const float*)d_in[6];
    const float* bv = (const float*)d_in[7];
    float* out = (float*)d_out;

    // Workspace: q(f32) | kv(u32) | cnt | row_start | bsum(512) | pos_e(ushort) | csr_dst
    float* q  = (float*)d_ws;
    uint*  kv = (uint*)(q + (size_t)N_NODES * OUT_FEATS);
    int* cnt       = (int*)(kv + (size_t)N_NODES * OUT_FEATS);
    int* row_start = cnt + N_NODES;
    int* bsum      = row_start + N_NODES;
    ushort* pos_e  = (ushort*)(bsum + 512);
    int* csr_dst   = (int*)(pos_e + E_EDGES);

    const int* src = edge;            // edge[0]
    const int* dst = edge + E_EDGES;  // edge[1]

    hipMemsetAsync(cnt, 0, N_NODES * sizeof(int), stream);

    qkv_hist_kernel<<<QKV_BLOCKS + HIST_BLOCKS, 256, 0, stream>>>(
        x, Wq, bq, Wk, bk, Wv, bv, q, kv, src, cnt, pos_e);

    scan1_kernel<<<SCAN1_BLOCKS, 256, 0, stream>>>(cnt, row_start, bsum);
    scan2_kernel<<<1, 128, 0, stream>>>(bsum);

    const int e4blocks = (E_EDGES / 4 + 255) / 256;
    csr_scatter_kernel<<<e4blocks, 256, 0, stream>>>(src, dst, row_start, bsum, pos_e, csr_dst);

    attn_kernel<<<N_NODES / 4, 256, 0, stream>>>(q, kv, row_start, bsum, cnt, csr_dst, out);
}